// Round 6
// baseline (36.778 us; speedup 1.0000x reference)
//
#include <hip/hip_runtime.h>

// SSIM map: refl-pad(1) + 3x3 avg-pool stencil, B=16 C=3 H=512 W=512 fp32.
// R5 post-mortem: latency-bound (31% HBM, 28% VALU, VGPR=24). Fix: float4
// per-thread column quad -> 6 VMEM per 4 outputs (was per 1), 4x ILP.

#define HH 512
#define WW 512
#define ROWS 8           // rows per thread-strip
#define SSIM_C1 1e-4f    // 0.01^2
#define SSIM_C2 9e-4f    // 0.03^2

typedef float f4 __attribute__((ext_vector_type(4)));

struct Hq { f4 sx, sy, sxx, syy, sxy; };   // horizontal 3-sums at 4 cols

__device__ __forceinline__ Hq load_row(const float* __restrict__ xr,
                                       const float* __restrict__ yr,
                                       int c0, int cm, int cp,
                                       bool le, bool re) {
    f4 fx = *(const f4*)(xr + c0);
    f4 fy = *(const f4*)(yr + c0);
    float xl = xr[cm], xrv = xr[cp];
    float yl = yr[cm], yrv = yr[cp];
    // column reflection-pad: col -1 -> col 1 (fx.y); col 512 -> col 510 (fx.z)
    xl  = le ? fx.y : xl;   yl  = le ? fy.y : yl;
    xrv = re ? fx.z : xrv;  yrv = re ? fy.z : yrv;

    Hq h;
    h.sx = (f4){ xl + fx.x + fx.y, fx.x + fx.y + fx.z,
                 fx.y + fx.z + fx.w, fx.z + fx.w + xrv };
    h.sy = (f4){ yl + fy.x + fy.y, fy.x + fy.y + fy.z,
                 fy.y + fy.z + fy.w, fy.z + fy.w + yrv };
    float a0 = xl*xl, a1 = fx.x*fx.x, a2 = fx.y*fx.y,
          a3 = fx.z*fx.z, a4 = fx.w*fx.w, a5 = xrv*xrv;
    h.sxx = (f4){ a0+a1+a2, a1+a2+a3, a2+a3+a4, a3+a4+a5 };
    float b0 = yl*yl, b1 = fy.x*fy.x, b2 = fy.y*fy.y,
          b3 = fy.z*fy.z, b4 = fy.w*fy.w, b5 = yrv*yrv;
    h.syy = (f4){ b0+b1+b2, b1+b2+b3, b2+b3+b4, b3+b4+b5 };
    float c0_ = xl*yl, c1 = fx.x*fy.x, c2 = fx.y*fy.y,
          c3 = fx.z*fy.z, c4 = fx.w*fy.w, c5 = xrv*yrv;
    h.sxy = (f4){ c0_+c1+c2, c1+c2+c3, c2+c3+c4, c3+c4+c5 };
    return h;
}

__global__ __launch_bounds__(256) void ssim_kernel(const float* __restrict__ x,
                                                   const float* __restrict__ y,
                                                   float* __restrict__ out) {
    const int t     = threadIdx.x;                 // 0..127 column-quad index
    const int c0    = t << 2;                      // first col (16B aligned)
    const int strip = blockIdx.y * 2 + threadIdx.y;
    const int row0  = strip * ROWS;
    const size_t po = (size_t)blockIdx.z * (size_t)(HH * WW);
    const float* xp = x + po;
    const float* yp = y + po;
    float* op       = out + po;

    const bool le = (c0 == 0);
    const bool re = (c0 + 4 == WW);
    const int  cm = le ? 0 : c0 - 1;               // clamped addrs (value fixed by select)
    const int  cp = re ? WW - 1 : c0 + 4;

    const float inv9 = 1.0f / 9.0f;

    // prime 2-row window (row reflection: -1 -> 1, 512 -> 510)
    int rA = (row0 - 1 < 0) ? 1 : row0 - 1;
    Hq h0 = load_row(xp + rA * WW, yp + rA * WW, c0, cm, cp, le, re);
    Hq h1 = load_row(xp + row0 * WW, yp + row0 * WW, c0, cm, cp, le, re);

    #pragma unroll 2
    for (int i = 0; i < ROWS; ++i) {
        const int r  = row0 + i;
        const int rn = (r + 1 >= HH) ? HH - 2 : r + 1;
        Hq h2 = load_row(xp + rn * WW, yp + rn * WW, c0, cm, cp, le, re);

        const f4 sx  = h0.sx  + h1.sx  + h2.sx;
        const f4 sy  = h0.sy  + h1.sy  + h2.sy;
        const f4 sxx = h0.sxx + h1.sxx + h2.sxx;
        const f4 syy = h0.syy + h1.syy + h2.syy;
        const f4 sxy = h0.sxy + h1.sxy + h2.sxy;

        const f4 mux   = sx * inv9;
        const f4 muy   = sy * inv9;
        const f4 sigx  = sxx * inv9 - mux * mux;
        const f4 sigy  = syy * inv9 - muy * muy;
        const f4 sigxy = sxy * inv9 - mux * muy;

        const f4 n = (2.0f * mux * muy + SSIM_C1) * (2.0f * sigxy + SSIM_C2);
        const f4 d = (mux * mux + muy * muy + SSIM_C1) * (sigx + sigy + SSIM_C2);
        f4 v = (1.0f - n / (d + 1e-8f)) * 0.5f;
        v.x = fminf(fmaxf(v.x, 0.0f), 1.0f);
        v.y = fminf(fmaxf(v.y, 0.0f), 1.0f);
        v.z = fminf(fmaxf(v.z, 0.0f), 1.0f);
        v.w = fminf(fmaxf(v.w, 0.0f), 1.0f);

        *(f4*)(op + (size_t)r * WW + c0) = v;

        h0 = h1;
        h1 = h2;
    }
}

extern "C" void kernel_launch(void* const* d_in, const int* in_sizes, int n_in,
                              void* d_out, int out_size, void* d_ws, size_t ws_size,
                              hipStream_t stream) {
    const float* x = (const float*)d_in[0];
    const float* y = (const float*)d_in[1];
    float* out     = (float*)d_out;

    // 48 planes of 512x512; 128 col-threads x 2 strips per block
    dim3 block(128, 2, 1);
    dim3 grid(1, HH / (ROWS * 2), 48);   // (1, 32, 48) = 1536 blocks
    ssim_kernel<<<grid, block, 0, stream>>>(x, y, out);
}